// Round 1
// baseline (1043.975 us; speedup 1.0000x reference)
//
#include <hip/hip_runtime.h>
#include <math.h>

#define BB 4
#define SS 2048
#define DD 512
#define NN 16
#define LL 4
#define VV 256
#define CC 64            // scan chunks
#define TT (SS / CC)     // 32 steps per chunk
#define EPSL 1e-5f

// ---------------- embed: X[b,s,d] = emb_byte[ids[b,s],d] + emb_pos[s,d] ----
__global__ void embed_kernel(const int* __restrict__ ids,
                             const float* __restrict__ eb,
                             const float* __restrict__ ep,
                             float* __restrict__ X) {
    int idx = blockIdx.x * 256 + threadIdx.x;      // over B*S*D
    int d = idx % DD;
    int s = (idx / DD) % SS;
    int b = idx / (DD * SS);
    X[idx] = eb[(size_t)ids[b * SS + s] * DD + d] + ep[(size_t)s * DD + d];
}

// ---------------- layernorm: one wave per row of D=512 --------------------
__global__ void ln_kernel(const float* __restrict__ X,
                          const float* __restrict__ gamma,
                          const float* __restrict__ beta,
                          float* __restrict__ HN) {
    int wave = threadIdx.x >> 6;
    int lane = threadIdx.x & 63;
    int row = blockIdx.x * 4 + wave;
    const float* xr = X + (size_t)row * DD;
    float4 v0 = *(const float4*)(xr + lane * 4);
    float4 v1 = *(const float4*)(xr + 256 + lane * 4);
    float s = v0.x + v0.y + v0.z + v0.w + v1.x + v1.y + v1.z + v1.w;
    float q = v0.x * v0.x + v0.y * v0.y + v0.z * v0.z + v0.w * v0.w +
              v1.x * v1.x + v1.y * v1.y + v1.z * v1.z + v1.w * v1.w;
#pragma unroll
    for (int o = 1; o < 64; o <<= 1) {
        s += __shfl_xor(s, o);
        q += __shfl_xor(q, o);
    }
    float m = s * (1.0f / DD);
    float var = q * (1.0f / DD) - m * m;
    float rs = rsqrtf(var + EPSL);
    float4 g0 = *(const float4*)(gamma + lane * 4);
    float4 g1 = *(const float4*)(gamma + 256 + lane * 4);
    float4 b0 = *(const float4*)(beta + lane * 4);
    float4 b1 = *(const float4*)(beta + 256 + lane * 4);
    float* hr = HN + (size_t)row * DD;
    float4 o0, o1;
    o0.x = (v0.x - m) * rs * g0.x + b0.x;
    o0.y = (v0.y - m) * rs * g0.y + b0.y;
    o0.z = (v0.z - m) * rs * g0.z + b0.z;
    o0.w = (v0.w - m) * rs * g0.w + b0.w;
    o1.x = (v1.x - m) * rs * g1.x + b1.x;
    o1.y = (v1.y - m) * rs * g1.y + b1.y;
    o1.z = (v1.z - m) * rs * g1.z + b1.z;
    o1.w = (v1.w - m) * rs * g1.w + b1.w;
    *(float4*)(hr + lane * 4) = o0;
    *(float4*)(hr + 256 + lane * 4) = o1;
}

// ---------------- big tiled fp32 GEMM: Out[M,Nout] = A[M,512] @ W[512,Nout] + bias
// MODE 0: plain   MODE 1: softplus   MODE 2: + Xtra (residual, Nout==DD)
template <int MODE>
__global__ __launch_bounds__(256) void gemm512(const float* __restrict__ Aa,
                                               const float* __restrict__ W,
                                               const float* __restrict__ bias,
                                               const float* __restrict__ Xtra,
                                               float* __restrict__ Out, int Nout) {
    __shared__ float As[16][68];
    __shared__ float Bs[16][68];
    int tid = threadIdx.x;
    int mblk = blockIdx.y, nblk = blockIdx.x;
    int tx = tid & 15, ty = tid >> 4;
    int arow = tid >> 2, akq = tid & 3;   // A: 64 rows x 16 k, one float4 per thread
    int brow = tid >> 4, bq = tid & 15;   // B: 16 k-rows x 64 cols
    float acc[4][4];
#pragma unroll
    for (int i = 0; i < 4; i++)
#pragma unroll
        for (int j = 0; j < 4; j++) acc[i][j] = 0.0f;

    const float* Abase = Aa + (size_t)(mblk * 64 + arow) * DD;
    for (int k0 = 0; k0 < DD; k0 += 16) {
        float4 av = *(const float4*)(Abase + k0 + akq * 4);
        As[akq * 4 + 0][arow] = av.x;
        As[akq * 4 + 1][arow] = av.y;
        As[akq * 4 + 2][arow] = av.z;
        As[akq * 4 + 3][arow] = av.w;
        float4 bv = *(const float4*)(W + (size_t)(k0 + brow) * Nout + nblk * 64 + bq * 4);
        *(float4*)&Bs[brow][bq * 4] = bv;
        __syncthreads();
#pragma unroll
        for (int k = 0; k < 16; k++) {
            float a4[4], b4[4];
            *(float4*)a4 = *(const float4*)&As[k][ty * 4];
            *(float4*)b4 = *(const float4*)&Bs[k][tx * 4];
#pragma unroll
            for (int i = 0; i < 4; i++)
#pragma unroll
                for (int j = 0; j < 4; j++) acc[i][j] = fmaf(a4[i], b4[j], acc[i][j]);
        }
        __syncthreads();
    }
    int row0 = mblk * 64 + ty * 4, col0 = nblk * 64 + tx * 4;
#pragma unroll
    for (int i = 0; i < 4; i++) {
#pragma unroll
        for (int j = 0; j < 4; j++) {
            float v = acc[i][j] + bias[col0 + j];
            if (MODE == 1) v = fmaxf(v, 0.0f) + log1pf(__expf(-fabsf(v)));
            if (MODE == 2) v += Xtra[(size_t)(row0 + i) * DD + col0 + j];
            Out[(size_t)(row0 + i) * Nout + col0 + j] = v;
        }
    }
}

// ---------------- small GEMM: Out[M,16] = A[M,512] @ W[512,16] + bias ------
__global__ void gemmN(const float* __restrict__ Aa, const float* __restrict__ W,
                      const float* __restrict__ bias, float* __restrict__ Out) {
    int tid = threadIdx.x;
    int col = tid & 15;
    int row = blockIdx.x * 16 + (tid >> 4);
    const float* ar = Aa + (size_t)row * DD;
    float acc = 0.0f;
#pragma unroll 8
    for (int k = 0; k < DD; k++) acc = fmaf(ar[k], W[k * NN + col], acc);
    Out[(size_t)row * NN + col] = acc + bias[col];
}

// ---------------- scan phase 1: per-(b,d,chunk) local scan from zero -------
__global__ __launch_bounds__(512) void scan1(const float* __restrict__ DEL,
                                             const float* __restrict__ HNp,
                                             const float* __restrict__ BI,
                                             const float* __restrict__ logA,
                                             float* __restrict__ P,
                                             float* __restrict__ LSt) {
    int b = blockIdx.x / CC, c = blockIdx.x % CC;
    int d = threadIdx.x;
    float Ar[NN], prod[NN], st[NN];
#pragma unroll
    for (int n = 0; n < NN; n++) {
        Ar[n] = -__expf(logA[d * NN + n]);
        prod[n] = 1.0f;
        st[n] = 0.0f;
    }
    int t0 = c * TT;
    for (int t = t0; t < t0 + TT; t++) {
        size_t base = (size_t)b * SS + t;
        float dl = DEL[base * DD + d];
        float du = dl * HNp[base * DD + d];
        const float* bi = BI + base * NN;
#pragma unroll
        for (int n = 0; n < NN; n++) {
            float a = __expf(dl * Ar[n]);
            prod[n] *= a;
            st[n] = fmaf(a, st[n], du * bi[n]);
        }
    }
    size_t o = (((size_t)b * DD + d) * CC + c) * NN;
#pragma unroll
    for (int n = 0; n < NN; n++) {
        P[o + n] = prod[n];
        LSt[o + n] = st[n];
    }
}

// ---------------- scan phase 2: sequential combine across chunks -----------
__global__ void scan2(const float* __restrict__ P, const float* __restrict__ LSt,
                      float* __restrict__ SIN) {
    int tid = blockIdx.x * 256 + threadIdx.x;  // over B*D*N = 32768
    int n = tid & (NN - 1);
    int d = (tid / NN) & (DD - 1);
    int b = tid / (NN * DD);
    size_t base = ((size_t)b * DD + d) * CC;
    float s = 0.0f;
    for (int c = 0; c < CC; c++) {
        size_t o = (base + c) * NN + n;
        SIN[o] = s;
        s = fmaf(P[o], s, LSt[o]);
    }
}

// ---------------- scan phase 3: re-scan with true initial state, emit y ----
__global__ __launch_bounds__(512) void scan3(const float* __restrict__ DEL,
                                             const float* __restrict__ HNp,
                                             const float* __restrict__ BI,
                                             const float* __restrict__ CI,
                                             const float* __restrict__ logA,
                                             const float* __restrict__ SIN,
                                             const float* __restrict__ D2,
                                             float* __restrict__ X) {
    int b = blockIdx.x / CC, c = blockIdx.x % CC;
    int d = threadIdx.x;
    float Ar[NN], st[NN];
    size_t o = (((size_t)b * DD + d) * CC + c) * NN;
#pragma unroll
    for (int n = 0; n < NN; n++) {
        Ar[n] = -__expf(logA[d * NN + n]);
        st[n] = SIN[o + n];
    }
    int t0 = c * TT;
    for (int t = t0; t < t0 + TT; t++) {
        size_t base = (size_t)b * SS + t;
        float dl = DEL[base * DD + d];
        float du = dl * HNp[base * DD + d];
        const float* bi = BI + base * NN;
        const float* ci = CI + base * NN;
        float y = 0.0f;
#pragma unroll
        for (int n = 0; n < NN; n++) {
            float a = __expf(dl * Ar[n]);
            st[n] = fmaf(a, st[n], du * bi[n]);
            y = fmaf(st[n], ci[n], y);
        }
        X[base * DD + d] = D2[base * DD + d] + y;
    }
}

extern "C" void kernel_launch(void* const* d_in, const int* in_sizes, int n_in,
                              void* d_out, int out_size, void* d_ws, size_t ws_size,
                              hipStream_t stream) {
    const int* ids = (const int*)d_in[0];
    const float* eb = (const float*)d_in[1];
    const float* ep = (const float*)d_in[2];
    const float* logA = (const float*)d_in[3];
    const float* Wd = (const float*)d_in[4];
    const float* bd = (const float*)d_in[5];
    const float* WB = (const float*)d_in[6];
    const float* bB = (const float*)d_in[7];
    const float* WC = (const float*)d_in[8];
    const float* bC = (const float*)d_in[9];
    const float* WDp = (const float*)d_in[10];
    const float* bDp = (const float*)d_in[11];
    const float* gamma = (const float*)d_in[12];
    const float* beta = (const float*)d_in[13];
    const float* Wh = (const float*)d_in[14];
    const float* bh = (const float*)d_in[15];
    float* out = (float*)d_out;

    size_t E = (size_t)BB * SS * DD;           // 4,194,304
    size_t EN = (size_t)BB * SS * NN;          // 131,072
    size_t EC = (size_t)BB * DD * CC * NN;     // 2,097,152
    float* X = (float*)d_ws;
    float* HN = X + E;
    float* DEL = HN + E;
    float* D2 = DEL + E;
    float* BIc = D2 + E;
    float* CIc = BIc + EN;
    float* P = CIc + EN;
    float* LS = P + EC;
    float* SI = LS + EC;

    embed_kernel<<<(BB * SS * DD) / 256, 256, 0, stream>>>(ids, eb, ep, X);
    for (int l = 0; l < LL; l++) {
        const float* lA = logA + (size_t)l * DD * NN;
        ln_kernel<<<(BB * SS) / 4, 256, 0, stream>>>(X, gamma + l * DD, beta + l * DD, HN);
        gemm512<1><<<dim3(DD / 64, (BB * SS) / 64), 256, 0, stream>>>(
            HN, Wd + (size_t)l * DD * DD, bd + l * DD, nullptr, DEL, DD);
        gemm512<2><<<dim3(DD / 64, (BB * SS) / 64), 256, 0, stream>>>(
            HN, WDp + (size_t)l * DD * DD, bDp + l * DD, X, D2, DD);
        gemmN<<<(BB * SS) / 16, 256, 0, stream>>>(HN, WB + (size_t)l * DD * NN, bB + l * NN, BIc);
        gemmN<<<(BB * SS) / 16, 256, 0, stream>>>(HN, WC + (size_t)l * DD * NN, bC + l * NN, CIc);
        scan1<<<BB * CC, 512, 0, stream>>>(DEL, HN, BIc, lA, P, LS);
        scan2<<<(BB * DD * NN) / 256, 256, 0, stream>>>(P, LS, SI);
        scan3<<<BB * CC, 512, 0, stream>>>(DEL, HN, BIc, CIc, lA, SI, D2, X);
    }
    gemm512<0><<<dim3(VV / 64, (BB * SS) / 64), 256, 0, stream>>>(X, Wh, bh, nullptr, out, VV);
}

// Round 2
// 709.772 us; speedup vs baseline: 1.4709x; 1.4709x over previous
//
#include <hip/hip_runtime.h>
#include <math.h>

#define BB 4
#define SS 2048
#define DD 512
#define NN 16
#define LL 4
#define VV 256
#define CC 64            // scan chunks
#define TT (SS / CC)     // 32 steps per chunk
#define EPSL 1e-5f
#define MM (BB * SS)     // 8192 rows

typedef __bf16 bf16;
typedef __attribute__((ext_vector_type(8))) __bf16 bf16x8;
typedef __attribute__((ext_vector_type(4))) __bf16 bf16x4;
typedef __attribute__((ext_vector_type(4))) float f32x4;

#define GLD_LDS(g, l) \
    __builtin_amdgcn_global_load_lds((__attribute__((address_space(1))) void*)(void*)(g), \
                                     (__attribute__((address_space(3))) void*)(l), 16, 0, 0)

// ---------------- embed: X[b,s,d] = emb_byte[ids[b,s],d] + emb_pos[s,d] ----
__global__ void embed_kernel(const int* __restrict__ ids,
                             const float* __restrict__ eb,
                             const float* __restrict__ ep,
                             float* __restrict__ X) {
    int idx = blockIdx.x * 256 + threadIdx.x;      // over B*S*D
    int d = idx % DD;
    int s = (idx / DD) % SS;
    int b = idx / (DD * SS);
    X[idx] = eb[(size_t)ids[b * SS + s] * DD + d] + ep[(size_t)s * DD + d];
}

// ---------------- weight convert+transpose: fp32 [K,N] -> bf16 [N,K] -------
// z: 0-3 Wd[l] -> WtL[l] rows 0-511 ; 4-7 WDp[l] -> WtL[l] rows 512-1023 ; 8 Wh -> WtH
__global__ void convert_weights(const float* __restrict__ Wd,
                                const float* __restrict__ WDp,
                                const float* __restrict__ Wh,
                                bf16* __restrict__ WtL, bf16* __restrict__ WtH) {
    int z = blockIdx.z;
    const float* src;
    bf16* dst;
    int Nsrc;
    if (z < 4)      { src = Wd + (size_t)z * DD * DD; dst = WtL + (size_t)z * 1024 * DD; Nsrc = DD; }
    else if (z < 8) { src = WDp + (size_t)(z - 4) * DD * DD; dst = WtL + (size_t)(z - 4) * 1024 * DD + (size_t)DD * DD; Nsrc = DD; }
    else            { src = Wh; dst = WtH; Nsrc = VV; }
    if (blockIdx.x * 32 >= (unsigned)Nsrc) return;
    __shared__ float t[32][33];
    int tx = threadIdx.x & 31, ty = threadIdx.x >> 5;   // 256 thr: ty 0..7
#pragma unroll
    for (int ii = 0; ii < 4; ii++) {
        int k = blockIdx.y * 32 + ty + ii * 8;
        t[ty + ii * 8][tx] = src[(size_t)k * Nsrc + blockIdx.x * 32 + tx];
    }
    __syncthreads();
#pragma unroll
    for (int ii = 0; ii < 4; ii++) {
        int n = blockIdx.x * 32 + ty + ii * 8;
        dst[(size_t)n * DD + blockIdx.y * 32 + tx] = (bf16)t[tx][ty + ii * 8];
    }
}

// ---------------- layernorm: one wave per row; writes fp32 HN and bf16 HNb -
__global__ void ln_kernel(const float* __restrict__ X,
                          const float* __restrict__ gamma,
                          const float* __restrict__ beta,
                          float* __restrict__ HN, bf16* __restrict__ HNb) {
    int wave = threadIdx.x >> 6;
    int lane = threadIdx.x & 63;
    int row = blockIdx.x * 4 + wave;
    const float* xr = X + (size_t)row * DD;
    float4 v0 = *(const float4*)(xr + lane * 4);
    float4 v1 = *(const float4*)(xr + 256 + lane * 4);
    float s = v0.x + v0.y + v0.z + v0.w + v1.x + v1.y + v1.z + v1.w;
    float q = v0.x * v0.x + v0.y * v0.y + v0.z * v0.z + v0.w * v0.w +
              v1.x * v1.x + v1.y * v1.y + v1.z * v1.z + v1.w * v1.w;
#pragma unroll
    for (int o = 1; o < 64; o <<= 1) {
        s += __shfl_xor(s, o);
        q += __shfl_xor(q, o);
    }
    float m = s * (1.0f / DD);
    float var = q * (1.0f / DD) - m * m;
    float rs = rsqrtf(var + EPSL);
    float4 g0 = *(const float4*)(gamma + lane * 4);
    float4 g1 = *(const float4*)(gamma + 256 + lane * 4);
    float4 b0 = *(const float4*)(beta + lane * 4);
    float4 b1 = *(const float4*)(beta + 256 + lane * 4);
    float* hr = HN + (size_t)row * DD;
    float4 o0, o1;
    o0.x = (v0.x - m) * rs * g0.x + b0.x;
    o0.y = (v0.y - m) * rs * g0.y + b0.y;
    o0.z = (v0.z - m) * rs * g0.z + b0.z;
    o0.w = (v0.w - m) * rs * g0.w + b0.w;
    o1.x = (v1.x - m) * rs * g1.x + b1.x;
    o1.y = (v1.y - m) * rs * g1.y + b1.y;
    o1.z = (v1.z - m) * rs * g1.z + b1.z;
    o1.w = (v1.w - m) * rs * g1.w + b1.w;
    *(float4*)(hr + lane * 4) = o0;
    *(float4*)(hr + 256 + lane * 4) = o1;
    bf16* hb = HNb + (size_t)row * DD;
    bf16x4 p0 = {(bf16)o0.x, (bf16)o0.y, (bf16)o0.z, (bf16)o0.w};
    bf16x4 p1 = {(bf16)o1.x, (bf16)o1.y, (bf16)o1.z, (bf16)o1.w};
    *(bf16x4*)(hb + lane * 4) = p0;
    *(bf16x4*)(hb + 256 + lane * 4) = p1;
}

// ---------------- bf16 MFMA GEMM, 128x128 tile, K=512, Wt is [N][K] --------
// MODE 0 (head): O1[row*Nout+col] = acc + bias[col]
// MODE 1 (fused layer, Nout=1024): col<512 -> DEL=softplus(acc+bias[col]);
//                                  col>=512 -> D2 = acc + bias2[c] + Xres[row,c]
template <int MODE>
__global__ __launch_bounds__(256) void gemm_mfma(const bf16* __restrict__ Ab,
                                                 const bf16* __restrict__ Wt,
                                                 const float* __restrict__ bias,
                                                 const float* __restrict__ bias2,
                                                 const float* __restrict__ Xres,
                                                 float* __restrict__ O1,
                                                 float* __restrict__ O2, int Nout) {
    __shared__ bf16 As[128 * 32];
    __shared__ bf16 Bs[128 * 32];
    const int tid = threadIdx.x;
    const int wave = tid >> 6, lane = tid & 63;
    const int m0 = blockIdx.y * 128, n0 = blockIdx.x * 128;

    // staging: each wave issues 2 A + 2 B global_load_lds (16B/lane)
    const char* gA[2];
    const char* gB[2];
    bf16* lA[2];
    bf16* lB[2];
#pragma unroll
    for (int inst = 0; inst < 2; inst++) {
        int fo = wave * 2048 + inst * 1024;       // wave-uniform byte base
        int fl = fo + lane * 16;                  // per-lane byte offset
        int row = fl >> 6;                        // 64B per 32-elem bf16 row
        int colb = fl & 63;
        gA[inst] = (const char*)Ab + (size_t)(m0 + row) * (DD * 2) + colb;
        gB[inst] = (const char*)Wt + (size_t)(n0 + row) * (DD * 2) + colb;
        lA[inst] = As + fo / 2;
        lB[inst] = Bs + fo / 2;
    }

    f32x4 acc[4][4];
#pragma unroll
    for (int i = 0; i < 4; i++)
#pragma unroll
        for (int j = 0; j < 4; j++) acc[i][j] = (f32x4){0.f, 0.f, 0.f, 0.f};

    const int wr = (wave >> 1) * 64, wc = (wave & 1) * 64;
    const int fm = lane & 15, fq = lane >> 4;
    const bf16* Ar = As + (wr + fm) * 32 + fq * 8;
    const bf16* Br = Bs + (wc + fm) * 32 + fq * 8;

    for (int k0 = 0; k0 < DD; k0 += 32) {
        GLD_LDS(gA[0] + k0 * 2, lA[0]);
        GLD_LDS(gA[1] + k0 * 2, lA[1]);
        GLD_LDS(gB[0] + k0 * 2, lB[0]);
        GLD_LDS(gB[1] + k0 * 2, lB[1]);
        __syncthreads();
        bf16x8 af[4], bfr[4];
#pragma unroll
        for (int i = 0; i < 4; i++) af[i] = *(const bf16x8*)(Ar + i * 16 * 32);
#pragma unroll
        for (int j = 0; j < 4; j++) bfr[j] = *(const bf16x8*)(Br + j * 16 * 32);
#pragma unroll
        for (int i = 0; i < 4; i++)
#pragma unroll
            for (int j = 0; j < 4; j++)
                acc[i][j] = __builtin_amdgcn_mfma_f32_16x16x32_bf16(af[i], bfr[j], acc[i][j], 0, 0, 0);
        __syncthreads();
    }

    const int row0 = m0 + wr, col0 = n0 + wc;
#pragma unroll
    for (int i = 0; i < 4; i++) {
#pragma unroll
        for (int j = 0; j < 4; j++) {
            int col = col0 + j * 16 + fm;
#pragma unroll
            for (int r = 0; r < 4; r++) {
                int row = row0 + i * 16 + fq * 4 + r;
                float v = acc[i][j][r];
                if (MODE == 0) {
                    O1[(size_t)row * Nout + col] = v + bias[col];
                } else {
                    if (col < DD) {
                        v += bias[col];
                        v = fmaxf(v, 0.0f) + log1pf(__expf(-fabsf(v)));
                        O1[(size_t)row * DD + col] = v;
                    } else {
                        int c = col - DD;
                        O2[(size_t)row * DD + c] = v + bias2[c] + Xres[(size_t)row * DD + c];
                    }
                }
            }
        }
    }
}

// ---------------- small GEMM: Out[M,16] = A[M,512] @ W[512,16] + bias ------
__global__ void gemmN(const float* __restrict__ Aa, const float* __restrict__ W,
                      const float* __restrict__ bias, float* __restrict__ Out) {
    int tid = threadIdx.x;
    int col = tid & 15;
    int row = blockIdx.x * 16 + (tid >> 4);
    const float* ar = Aa + (size_t)row * DD;
    float acc = 0.0f;
#pragma unroll 8
    for (int k = 0; k < DD; k++) acc = fmaf(ar[k], W[k * NN + col], acc);
    Out[(size_t)row * NN + col] = acc + bias[col];
}

// ---------------- scan phase 1: per-(b,d,chunk) local scan from zero -------
__global__ __launch_bounds__(512) void scan1(const float* __restrict__ DEL,
                                             const float* __restrict__ HNp,
                                             const float* __restrict__ BI,
                                             const float* __restrict__ logA,
                                             float* __restrict__ P,
                                             float* __restrict__ LSt) {
    int b = blockIdx.x / CC, c = blockIdx.x % CC;
    int d = threadIdx.x;
    float Ar[NN], prod[NN], st[NN];
#pragma unroll
    for (int n = 0; n < NN; n++) {
        Ar[n] = -__expf(logA[d * NN + n]);
        prod[n] = 1.0f;
        st[n] = 0.0f;
    }
    int t0 = c * TT;
    for (int t = t0; t < t0 + TT; t++) {
        size_t base = (size_t)b * SS + t;
        float dl = DEL[base * DD + d];
        float du = dl * HNp[base * DD + d];
        const float* bi = BI + base * NN;
#pragma unroll
        for (int n = 0; n < NN; n++) {
            float a = __expf(dl * Ar[n]);
            prod[n] *= a;
            st[n] = fmaf(a, st[n], du * bi[n]);
        }
    }
    size_t o = (((size_t)b * DD + d) * CC + c) * NN;
#pragma unroll
    for (int n = 0; n < NN; n++) {
        P[o + n] = prod[n];
        LSt[o + n] = st[n];
    }
}

// ---------------- scan phase 2: sequential combine; LS becomes init state --
__global__ void scan2(const float* __restrict__ P, float* __restrict__ LS) {
    int tid = blockIdx.x * 256 + threadIdx.x;  // over B*D*N = 32768
    int n = tid & (NN - 1);
    int d = (tid / NN) & (DD - 1);
    int b = tid / (NN * DD);
    size_t base = ((size_t)b * DD + d) * CC;
    float s = 0.0f;
    for (int c = 0; c < CC; c++) {
        size_t o = base * NN + (size_t)c * NN + n;
        float p = P[o];
        float ls = LS[o];
        LS[o] = s;                 // in-place: becomes chunk-initial state
        s = fmaf(p, s, ls);
    }
}

// ---------------- scan phase 3: re-scan with true init, emit X (+bf16 copy)
__global__ __launch_bounds__(512) void scan3(const float* __restrict__ DEL,
                                             const float* __restrict__ HNp,
                                             const float* __restrict__ BI,
                                             const float* __restrict__ CI,
                                             const float* __restrict__ logA,
                                             const float* __restrict__ SIN,
                                             const float* __restrict__ D2,
                                             float* __restrict__ X,
                                             bf16* __restrict__ XB) {
    int b = blockIdx.x / CC, c = blockIdx.x % CC;
    int d = threadIdx.x;
    float Ar[NN], st[NN];
    size_t o = (((size_t)b * DD + d) * CC + c) * NN;
#pragma unroll
    for (int n = 0; n < NN; n++) {
        Ar[n] = -__expf(logA[d * NN + n]);
        st[n] = SIN[o + n];
    }
    int t0 = c * TT;
    for (int t = t0; t < t0 + TT; t++) {
        size_t base = (size_t)b * SS + t;
        float dl = DEL[base * DD + d];
        float du = dl * HNp[base * DD + d];
        const float* bi = BI + base * NN;
        const float* ci = CI + base * NN;
        float y = 0.0f;
#pragma unroll
        for (int n = 0; n < NN; n++) {
            float a = __expf(dl * Ar[n]);
            st[n] = fmaf(a, st[n], du * bi[n]);
            y = fmaf(st[n], ci[n], y);
        }
        float xv = D2[base * DD + d] + y;
        X[base * DD + d] = xv;
        XB[base * DD + d] = (bf16)xv;
    }
}

extern "C" void kernel_launch(void* const* d_in, const int* in_sizes, int n_in,
                              void* d_out, int out_size, void* d_ws, size_t ws_size,
                              hipStream_t stream) {
    const int* ids = (const int*)d_in[0];
    const float* eb = (const float*)d_in[1];
    const float* ep = (const float*)d_in[2];
    const float* logA = (const float*)d_in[3];
    const float* Wd = (const float*)d_in[4];
    const float* bd = (const float*)d_in[5];
    const float* WB = (const float*)d_in[6];
    const float* bB = (const float*)d_in[7];
    const float* WC = (const float*)d_in[8];
    const float* bC = (const float*)d_in[9];
    const float* WDp = (const float*)d_in[10];
    const float* bDp = (const float*)d_in[11];
    const float* gamma = (const float*)d_in[12];
    const float* beta = (const float*)d_in[13];
    const float* Wh = (const float*)d_in[14];
    const float* bh = (const float*)d_in[15];
    float* out = (float*)d_out;

    size_t E = (size_t)MM * DD;                // 4,194,304 floats
    size_t EN = (size_t)MM * NN;               // 131,072
    size_t EC = (size_t)BB * DD * CC * NN;     // 2,097,152
    float* X = (float*)d_ws;
    float* HN = X + E;
    float* DEL = HN + E;
    float* D2 = DEL + E;
    float* BIc = D2 + E;
    float* CIc = BIc + EN;
    float* P = CIc + EN;
    float* LS = P + EC;
    bf16* HNb = (bf16*)(LS + EC);              // E bf16 = 8 MB
    bf16* WtL = HNb + E;                       // 4 layers x [1024][512] bf16
    bf16* WtH = WtL + (size_t)LL * 1024 * DD;  // [256][512] bf16

    embed_kernel<<<(MM * DD) / 256, 256, 0, stream>>>(ids, eb, ep, X);
    convert_weights<<<dim3(16, 16, 9), 256, 0, stream>>>(Wd, WDp, Wh, WtL, WtH);
    for (int l = 0; l < LL; l++) {
        const float* lA = logA + (size_t)l * DD * NN;
        ln_kernel<<<MM / 4, 256, 0, stream>>>(X, gamma + l * DD, beta + l * DD, HN, HNb);
        gemm_mfma<1><<<dim3(1024 / 128, MM / 128), 256, 0, stream>>>(
            HNb, WtL + (size_t)l * 1024 * DD, bd + l * DD, bDp + l * DD, X, DEL, D2, 1024);
        gemmN<<<MM / 16, 256, 0, stream>>>(HN, WB + (size_t)l * DD * NN, bB + l * NN, BIc);
        gemmN<<<MM / 16, 256, 0, stream>>>(HN, WC + (size_t)l * DD * NN, bC + l * NN, CIc);
        scan1<<<BB * CC, 512, 0, stream>>>(DEL, HN, BIc, lA, P, LS);
        scan2<<<(BB * DD * NN) / 256, 256, 0, stream>>>(P, LS);
        scan3<<<BB * CC, 512, 0, stream>>>(DEL, HN, BIc, CIc, lA, LS, D2, X, HNb);
    }
    // head: reads HNb = bf16(X_final) written by last scan3
    gemm_mfma<0><<<dim3(VV / 128, MM / 128), 256, 0, stream>>>(
        HNb, WtH, bh, nullptr, nullptr, out, nullptr, VV);
}

// Round 3
// 578.834 us; speedup vs baseline: 1.8036x; 1.2262x over previous
//
#include <hip/hip_runtime.h>
#include <math.h>

#define BB 4
#define SS 2048
#define DD 512
#define NN 16
#define LL 4
#define VV 256
#define CC 64            // scan chunks
#define TT (SS / CC)     // 32 steps per chunk
#define EPSL 1e-5f
#define MM (BB * SS)     // 8192 rows

typedef __bf16 bf16;
typedef __attribute__((ext_vector_type(8))) __bf16 bf16x8;
typedef __attribute__((ext_vector_type(4))) __bf16 bf16x4;
typedef __attribute__((ext_vector_type(4))) float f32x4;

#define GLD_LDS(g, l) \
    __builtin_amdgcn_global_load_lds((__attribute__((address_space(1))) void*)(void*)(g), \
                                     (__attribute__((address_space(3))) void*)(l), 16, 0, 0)

// ---------------- embed: X[b,s,d] = emb_byte[ids[b,s],d] + emb_pos[s,d] ----
__global__ void embed_kernel(const int* __restrict__ ids,
                             const float* __restrict__ eb,
                             const float* __restrict__ ep,
                             float* __restrict__ X) {
    int idx = blockIdx.x * 256 + threadIdx.x;      // over B*S*D
    int d = idx % DD;
    int s = (idx / DD) % SS;
    int b = idx / (DD * SS);
    X[idx] = eb[(size_t)ids[b * SS + s] * DD + d] + ep[(size_t)s * DD + d];
}

// ---------------- weight convert+transpose: fp32 [K,N] -> bf16 [N,K] -------
// z: 0-3 Wd[l] -> WtL[l] rows 0-511 ; 4-7 WDp[l] -> WtL[l] rows 512-1023 ; 8 Wh -> WtH
__global__ void convert_weights(const float* __restrict__ Wd,
                                const float* __restrict__ WDp,
                                const float* __restrict__ Wh,
                                bf16* __restrict__ WtL, bf16* __restrict__ WtH) {
    int z = blockIdx.z;
    const float* src;
    bf16* dst;
    int Nsrc;
    if (z < 4)      { src = Wd + (size_t)z * DD * DD; dst = WtL + (size_t)z * 1024 * DD; Nsrc = DD; }
    else if (z < 8) { src = WDp + (size_t)(z - 4) * DD * DD; dst = WtL + (size_t)(z - 4) * 1024 * DD + (size_t)DD * DD; Nsrc = DD; }
    else            { src = Wh; dst = WtH; Nsrc = VV; }
    if (blockIdx.x * 32 >= (unsigned)Nsrc) return;
    __shared__ float t[32][33];
    int tx = threadIdx.x & 31, ty = threadIdx.x >> 5;   // 256 thr: ty 0..7
#pragma unroll
    for (int ii = 0; ii < 4; ii++) {
        int k = blockIdx.y * 32 + ty + ii * 8;
        t[ty + ii * 8][tx] = src[(size_t)k * Nsrc + blockIdx.x * 32 + tx];
    }
    __syncthreads();
#pragma unroll
    for (int ii = 0; ii < 4; ii++) {
        int n = blockIdx.x * 32 + ty + ii * 8;
        dst[(size_t)n * DD + blockIdx.y * 32 + tx] = (bf16)t[tx][ty + ii * 8];
    }
}

// ---------------- layernorm: one wave per row; writes fp32 HN and bf16 HNb -
__global__ void ln_kernel(const float* __restrict__ X,
                          const float* __restrict__ gamma,
                          const float* __restrict__ beta,
                          float* __restrict__ HN, bf16* __restrict__ HNb) {
    int wave = threadIdx.x >> 6;
    int lane = threadIdx.x & 63;
    int row = blockIdx.x * 4 + wave;
    const float* xr = X + (size_t)row * DD;
    float4 v0 = *(const float4*)(xr + lane * 4);
    float4 v1 = *(const float4*)(xr + 256 + lane * 4);
    float s = v0.x + v0.y + v0.z + v0.w + v1.x + v1.y + v1.z + v1.w;
    float q = v0.x * v0.x + v0.y * v0.y + v0.z * v0.z + v0.w * v0.w +
              v1.x * v1.x + v1.y * v1.y + v1.z * v1.z + v1.w * v1.w;
#pragma unroll
    for (int o = 1; o < 64; o <<= 1) {
        s += __shfl_xor(s, o);
        q += __shfl_xor(q, o);
    }
    float m = s * (1.0f / DD);
    float var = q * (1.0f / DD) - m * m;
    float rs = rsqrtf(var + EPSL);
    float4 g0 = *(const float4*)(gamma + lane * 4);
    float4 g1 = *(const float4*)(gamma + 256 + lane * 4);
    float4 b0 = *(const float4*)(beta + lane * 4);
    float4 b1 = *(const float4*)(beta + 256 + lane * 4);
    float* hr = HN + (size_t)row * DD;
    float4 o0, o1;
    o0.x = (v0.x - m) * rs * g0.x + b0.x;
    o0.y = (v0.y - m) * rs * g0.y + b0.y;
    o0.z = (v0.z - m) * rs * g0.z + b0.z;
    o0.w = (v0.w - m) * rs * g0.w + b0.w;
    o1.x = (v1.x - m) * rs * g1.x + b1.x;
    o1.y = (v1.y - m) * rs * g1.y + b1.y;
    o1.z = (v1.z - m) * rs * g1.z + b1.z;
    o1.w = (v1.w - m) * rs * g1.w + b1.w;
    *(float4*)(hr + lane * 4) = o0;
    *(float4*)(hr + 256 + lane * 4) = o1;
    bf16* hb = HNb + (size_t)row * DD;
    bf16x4 p0 = {(bf16)o0.x, (bf16)o0.y, (bf16)o0.z, (bf16)o0.w};
    bf16x4 p1 = {(bf16)o1.x, (bf16)o1.y, (bf16)o1.z, (bf16)o1.w};
    *(bf16x4*)(hb + lane * 4) = p0;
    *(bf16x4*)(hb + 256 + lane * 4) = p1;
}

// ---------------- bf16 MFMA GEMM, 64x128 tile, K=512, Wt is [N][K] ---------
// Grid: 128*NT blocks (1D). XCD swizzle: all NT n-tiles of one m-tile land on
// one XCD (lin&7), so the A m-tile is fetched into that XCD's L2 once.
// MODE 0 (head): O1[row*Nout+col] = acc + bias[col]
// MODE 1 (fused layer, Nout=1024): col<512 -> DEL=softplus(acc+bias[col]);
//                                  col>=512 -> D2 = acc + bias2[c] + Xres[row,c]
template <int MODE>
__global__ __launch_bounds__(256) void gemm_mfma(const bf16* __restrict__ Ab,
                                                 const bf16* __restrict__ Wt,
                                                 const float* __restrict__ bias,
                                                 const float* __restrict__ bias2,
                                                 const float* __restrict__ Xres,
                                                 float* __restrict__ O1,
                                                 float* __restrict__ O2, int Nout) {
    __shared__ bf16 As[64 * 32];    // 4 KB
    __shared__ bf16 Bs[128 * 32];   // 8 KB
    const int tid = threadIdx.x;
    const int wave = tid >> 6, lane = tid & 63;
    // XCD-aware swizzle (m-tiles fixed at 128: M=8192, TM=64)
    const int lin = blockIdx.x;
    const int xcd = lin & 7;
    const int i4 = lin >> 3;
    const int m0 = (xcd * 16 + (i4 & 15)) * 64;
    const int n0 = (i4 >> 4) * 128;

    // staging: per wave 1 A-inst (1 KB) + 2 B-insts (2 KB), 16B/lane
    const char* gA;
    const char* gB[2];
    bf16* lA;
    bf16* lB[2];
    {
        int fo = wave * 1024;
        int fl = fo + lane * 16;
        gA = (const char*)Ab + (size_t)(m0 + (fl >> 6)) * (DD * 2) + (fl & 63);
        lA = As + fo / 2;
    }
#pragma unroll
    for (int inst = 0; inst < 2; inst++) {
        int fo = wave * 2048 + inst * 1024;
        int fl = fo + lane * 16;
        gB[inst] = (const char*)Wt + (size_t)(n0 + (fl >> 6)) * (DD * 2) + (fl & 63);
        lB[inst] = Bs + fo / 2;
    }

    f32x4 acc[2][4];
#pragma unroll
    for (int i = 0; i < 2; i++)
#pragma unroll
        for (int j = 0; j < 4; j++) acc[i][j] = (f32x4){0.f, 0.f, 0.f, 0.f};

    const int wr = (wave >> 1) * 32, wc = (wave & 1) * 64;
    const int fm = lane & 15, fq = lane >> 4;
    const bf16* Ar = As + (wr + fm) * 32 + fq * 8;
    const bf16* Br = Bs + (wc + fm) * 32 + fq * 8;

    for (int k0 = 0; k0 < DD; k0 += 32) {
        GLD_LDS(gA + k0 * 2, lA);
        GLD_LDS(gB[0] + k0 * 2, lB[0]);
        GLD_LDS(gB[1] + k0 * 2, lB[1]);
        __syncthreads();
        bf16x8 af[2], bfr[4];
#pragma unroll
        for (int i = 0; i < 2; i++) af[i] = *(const bf16x8*)(Ar + i * 16 * 32);
#pragma unroll
        for (int j = 0; j < 4; j++) bfr[j] = *(const bf16x8*)(Br + j * 16 * 32);
#pragma unroll
        for (int i = 0; i < 2; i++)
#pragma unroll
            for (int j = 0; j < 4; j++)
                acc[i][j] = __builtin_amdgcn_mfma_f32_16x16x32_bf16(af[i], bfr[j], acc[i][j], 0, 0, 0);
        __syncthreads();
    }

    const int row0 = m0 + wr, col0 = n0 + wc;
#pragma unroll
    for (int i = 0; i < 2; i++) {
#pragma unroll
        for (int j = 0; j < 4; j++) {
            int col = col0 + j * 16 + fm;
#pragma unroll
            for (int r = 0; r < 4; r++) {
                int row = row0 + i * 16 + fq * 4 + r;
                float v = acc[i][j][r];
                if (MODE == 0) {
                    O1[(size_t)row * Nout + col] = v + bias[col];
                } else {
                    if (col < DD) {
                        v += bias[col];
                        v = fmaxf(v, 0.0f) + log1pf(__expf(-fabsf(v)));
                        O1[(size_t)row * DD + col] = v;
                    } else {
                        int c = col - DD;
                        O2[(size_t)row * DD + c] = v + bias2[c] + Xres[(size_t)row * DD + c];
                    }
                }
            }
        }
    }
}

// ---------------- fused small GEMMs: BI/CI[M,16] = HN @ {WB,WC} + bias -----
__global__ void gemmBC(const float* __restrict__ HN,
                       const float* __restrict__ WB, const float* __restrict__ bB,
                       const float* __restrict__ WC, const float* __restrict__ bC,
                       float* __restrict__ BI, float* __restrict__ CI) {
    int tid = threadIdx.x;
    int col = tid & 15;
    int row = blockIdx.x * 16 + (tid >> 4);
    const float* ar = HN + (size_t)row * DD;
    float accB = 0.0f, accC = 0.0f;
#pragma unroll 8
    for (int k = 0; k < DD; k++) {
        float a = ar[k];
        accB = fmaf(a, WB[k * NN + col], accB);
        accC = fmaf(a, WC[k * NN + col], accC);
    }
    BI[(size_t)row * NN + col] = accB + bB[col];
    CI[(size_t)row * NN + col] = accC + bC[col];
}

// ---------------- scan phase 1: per-(b,d,chunk) local scan from zero -------
__global__ __launch_bounds__(512) void scan1(const float* __restrict__ DEL,
                                             const float* __restrict__ HNp,
                                             const float* __restrict__ BI,
                                             const float* __restrict__ logA,
                                             float* __restrict__ P,
                                             float* __restrict__ LSt) {
    int b = blockIdx.x / CC, c = blockIdx.x % CC;
    int d = threadIdx.x;
    float Ar[NN], prod[NN], st[NN];
#pragma unroll
    for (int n = 0; n < NN; n++) {
        Ar[n] = -__expf(logA[d * NN + n]);
        prod[n] = 1.0f;
        st[n] = 0.0f;
    }
    int t0 = c * TT;
    for (int t = t0; t < t0 + TT; t++) {
        size_t base = (size_t)b * SS + t;
        float dl = DEL[base * DD + d];
        float du = dl * HNp[base * DD + d];
        const float* bi = BI + base * NN;
#pragma unroll
        for (int n = 0; n < NN; n++) {
            float a = __expf(dl * Ar[n]);
            prod[n] *= a;
            st[n] = fmaf(a, st[n], du * bi[n]);
        }
    }
    size_t o = (((size_t)b * DD + d) * CC + c) * NN;
#pragma unroll
    for (int n = 0; n < NN; n++) {
        P[o + n] = prod[n];
        LSt[o + n] = st[n];
    }
}

// ---------------- scan phase 2: sequential combine; LS becomes init state --
__global__ void scan2(const float* __restrict__ P, float* __restrict__ LS) {
    int tid = blockIdx.x * 256 + threadIdx.x;  // over B*D*N = 32768
    int n = tid & (NN - 1);
    int d = (tid / NN) & (DD - 1);
    int b = tid / (NN * DD);
    size_t base = ((size_t)b * DD + d) * CC;
    float s = 0.0f;
    for (int c = 0; c < CC; c++) {
        size_t o = base * NN + (size_t)c * NN + n;
        float p = P[o];
        float ls = LS[o];
        LS[o] = s;                 // in-place: becomes chunk-initial state
        s = fmaf(p, s, ls);
    }
}

// ---------------- scan phase 3: re-scan with true init, emit X (+bf16 copy)
__global__ __launch_bounds__(512) void scan3(const float* __restrict__ DEL,
                                             const float* __restrict__ HNp,
                                             const float* __restrict__ BI,
                                             const float* __restrict__ CI,
                                             const float* __restrict__ logA,
                                             const float* __restrict__ SIN,
                                             const float* __restrict__ D2,
                                             float* __restrict__ X,
                                             bf16* __restrict__ XB) {
    int b = blockIdx.x / CC, c = blockIdx.x % CC;
    int d = threadIdx.x;
    float Ar[NN], st[NN];
    size_t o = (((size_t)b * DD + d) * CC + c) * NN;
#pragma unroll
    for (int n = 0; n < NN; n++) {
        Ar[n] = -__expf(logA[d * NN + n]);
        st[n] = SIN[o + n];
    }
    int t0 = c * TT;
    for (int t = t0; t < t0 + TT; t++) {
        size_t base = (size_t)b * SS + t;
        float dl = DEL[base * DD + d];
        float du = dl * HNp[base * DD + d];
        const float* bi = BI + base * NN;
        const float* ci = CI + base * NN;
        float y = 0.0f;
#pragma unroll
        for (int n = 0; n < NN; n++) {
            float a = __expf(dl * Ar[n]);
            st[n] = fmaf(a, st[n], du * bi[n]);
            y = fmaf(st[n], ci[n], y);
        }
        float xv = D2[base * DD + d] + y;
        X[base * DD + d] = xv;
        XB[base * DD + d] = (bf16)xv;
    }
}

extern "C" void kernel_launch(void* const* d_in, const int* in_sizes, int n_in,
                              void* d_out, int out_size, void* d_ws, size_t ws_size,
                              hipStream_t stream) {
    const int* ids = (const int*)d_in[0];
    const float* eb = (const float*)d_in[1];
    const float* ep = (const float*)d_in[2];
    const float* logA = (const float*)d_in[3];
    const float* Wd = (const float*)d_in[4];
    const float* bd = (const float*)d_in[5];
    const float* WB = (const float*)d_in[6];
    const float* bB = (const float*)d_in[7];
    const float* WC = (const float*)d_in[8];
    const float* bC = (const float*)d_in[9];
    const float* WDp = (const float*)d_in[10];
    const float* bDp = (const float*)d_in[11];
    const float* gamma = (const float*)d_in[12];
    const float* beta = (const float*)d_in[13];
    const float* Wh = (const float*)d_in[14];
    const float* bh = (const float*)d_in[15];
    float* out = (float*)d_out;

    size_t E = (size_t)MM * DD;                // 4,194,304 floats
    size_t EN = (size_t)MM * NN;               // 131,072
    size_t EC = (size_t)BB * DD * CC * NN;     // 2,097,152
    float* X = (float*)d_ws;
    float* HN = X + E;
    float* DEL = HN + E;
    float* D2 = DEL + E;
    float* BIc = D2 + E;
    float* CIc = BIc + EN;
    float* P = CIc + EN;
    float* LS = P + EC;
    bf16* HNb = (bf16*)(LS + EC);              // E bf16 = 8 MB
    bf16* WtL = HNb + E;                       // 4 layers x [1024][512] bf16
    bf16* WtH = WtL + (size_t)LL * 1024 * DD;  // [256][512] bf16

    embed_kernel<<<(MM * DD) / 256, 256, 0, stream>>>(ids, eb, ep, X);
    convert_weights<<<dim3(16, 16, 9), 256, 0, stream>>>(Wd, WDp, Wh, WtL, WtH);
    for (int l = 0; l < LL; l++) {
        const float* lA = logA + (size_t)l * DD * NN;
        ln_kernel<<<MM / 4, 256, 0, stream>>>(X, gamma + l * DD, beta + l * DD, HN, HNb);
        gemm_mfma<1><<<128 * (1024 / 128), 256, 0, stream>>>(
            HNb, WtL + (size_t)l * 1024 * DD, bd + l * DD, bDp + l * DD, X, DEL, D2, 1024);
        gemmBC<<<MM / 16, 256, 0, stream>>>(HN, WB + (size_t)l * DD * NN, bB + l * NN,
                                            WC + (size_t)l * DD * NN, bC + l * NN, BIc, CIc);
        scan1<<<BB * CC, 512, 0, stream>>>(DEL, HN, BIc, lA, P, LS);
        scan2<<<(BB * DD * NN) / 256, 256, 0, stream>>>(P, LS);
        scan3<<<BB * CC, 512, 0, stream>>>(DEL, HN, BIc, CIc, lA, LS, D2, X, HNb);
    }
    // head: reads HNb = bf16(X_final) written by last scan3
    gemm_mfma<0><<<128 * (VV / 128), 256, 0, stream>>>(
        HNb, WtH, bh, nullptr, nullptr, out, nullptr, VV);
}